// Round 6
// baseline (2055.657 us; speedup 1.0000x reference)
//
#include <hip/hip_runtime.h>

// RandomMFGL: out[o][g] = (1/4) * sum_n [ (A[n] @ x) @ W[n] + b[n] ]
// A: [4][4096][16384] fp32 = 1.07 GB streamed once -> HBM floor ~170us.
//
// v5: measured so far: v1 k_main ~660us (1.6 TB/s), k_rot probe 551us
// (1.9 TB/s, direct additive timing), v3b +139. All keep 64KB-strided row
// streams with <=256B per row-visit -> ~1 DRAM activate per 64B request
// (row-buffer-miss-bound, ~25-30% read efficiency). The 6.3 TB/s fill is
// sequential (row-hits). Fix: per wave-instr, stage 1KB CONTIGUOUS of A
// via global_load_lds (width 16): tile = 64 rows x 128 i (32KB), 32 instrs
// back-to-back (instr k = rows 2k,2k+1 x 512B) -> deep channel queues,
// long row-hit runs. Compute keeps v1's proven core: lane=row, x delivered
// wave-uniform via s_load (v1==v2 exonerated it). LDS 32-way conflict fixed
// by XOR-swizzling the 16B-unit index with row&7 -- applied on the GLOBAL
// source (global_load_lds dest is linear, rule: both-sides-or-neither) and
// on the ds_read address. Per-wave private double-buffer, NO barriers:
// counted s_waitcnt vmcnt(32) only (vmcnt is per-wave; wave reads only LDS
// it wrote itself -> race-free by construction). Block = 2 waves, 128KB LDS,
// 1 block/CU; VALU floor 109us << DRAM target. Split-K 32 -> 4.

#define N_ENS 4
#define N_OUT 4096
#define N_IN  16384
#define ROWS  (N_ENS * N_OUT)      // 16384 rows (row = n*4096 + o)
#define SPLITS 4                   // split-K factor
#define KCH   (N_IN / SPLITS)      // 4096 i per job
#define TI    128                  // i per tile (512 B per row)
#define NT    (KCH / TI)           // 32 tiles
#define TROWS 64                   // rows per wave

// ---------------- kernel 1: hp[split][row][f] = sum_{i in chunk} A[row][i] * x[i][f] ----------------
__global__ __launch_bounds__(128) void k_main(const float* __restrict__ A,
                                              const float* __restrict__ x,
                                              float* __restrict__ hp) {
    __shared__ float smem[2 * 2 * 8192];            // 2 waves x 2 bufs x 32KB = 128KB

    const int split = blockIdx.x & (SPLITS - 1);    // 0..3
    const int rowg  = blockIdx.x >> 2;              // 0..127
    const int wave  = threadIdx.x >> 6;             // 0..1
    const int lane  = threadIdx.x & 63;
    const int i0    = split * KCH;
    const int row0  = rowg * 128 + wave * TROWS;    // wave's first row

    float* lds = smem + wave * 16384;               // this wave's 64KB (2 bufs x 8192 floats)
    const float* Aw = A + (size_t)row0 * N_IN + i0; // wave-uniform base

    // stage tile t into buf: 32 x global_load_lds (1KB each = rows 2k,2k+1 x 512B).
    // LDS dest is linear (base + lane*16); the row&7 XOR swizzle is applied to
    // the GLOBAL source unit index so phys unit p of row r holds logical p^(r&7).
#define STAGE(buf, t) do {                                                    \
        const float* Asrc = Aw + (size_t)(t) * TI;                            \
        _Pragma("unroll")                                                     \
        for (int k = 0; k < 32; ++k) {                                        \
            const int r = 2 * k + (lane >> 5);                                \
            const int j = (lane & 31) ^ (r & 7);     /* logical 16B unit */   \
            const float* src = Asrc + (size_t)r * N_IN + j * 4;               \
            __builtin_amdgcn_global_load_lds(                                 \
                (const __attribute__((address_space(1))) void*)src,           \
                (__attribute__((address_space(3))) void*)&lds[(buf) * 8192 + k * 256], \
                16, 0, 0);                                                    \
        }                                                                     \
    } while (0)

    // compute tile t from buf: lane = row; A via swizzled ds_read_b128;
    // x wave-uniform -> scalar loads feed FMAs directly (v1's proven path).
#define COMPUTE(buf, t) do {                                                  \
        const float* xpt = x + (size_t)(i0 + (t) * TI) * 16;                  \
        _Pragma("unroll")                                                     \
        for (int c = 0; c < 4; ++c) {                                         \
            float4 a4[8];                                                     \
            _Pragma("unroll")                                                 \
            for (int e = 0; e < 8; ++e)                                       \
                a4[e] = *(const float4*)&lds[(buf) * 8192 + lane * 128 +      \
                                             (c * 8 + (e ^ (lane & 7))) * 4]; \
            const float* af = (const float*)a4;     /* logical i order */     \
            const float* xp = xpt + (size_t)c * 512;                          \
            _Pragma("unroll")                                                 \
            for (int ii = 0; ii < 32; ++ii) {                                 \
                const float av = af[ii];                                      \
                _Pragma("unroll")                                             \
                for (int f = 0; f < 16; ++f)                                  \
                    acc[f] = fmaf(av, xp[ii * 16 + f], acc[f]);               \
            }                                                                 \
        }                                                                     \
    } while (0)

    float acc[16];
#pragma unroll
    for (int f = 0; f < 16; ++f) acc[f] = 0.0f;

    STAGE(0, 0);                                    // prologue: tile 0 in flight

    for (int t = 0; t < NT; ++t) {
        if (t + 1 < NT) {
            STAGE((t + 1) & 1, t + 1);              // issue next tile (32 loads)
            // wait for CURRENT tile's 32 loads (next tile's 32 may remain in flight)
            asm volatile("s_waitcnt vmcnt(32)" ::: "memory");
        } else {
            asm volatile("s_waitcnt vmcnt(0)" ::: "memory");
        }
        __builtin_amdgcn_sched_barrier(0);          // rule 18: pin ds_reads after the wait
        COMPUTE(t & 1, t);
    }
#undef STAGE
#undef COMPUTE

    const int row = row0 + lane;
    float* outp = hp + ((size_t)split * ROWS + row) * 16;   // 64 B per lane, contiguous
#pragma unroll
    for (int f = 0; f < 16; ++f) outp[f] = acc[f];
}

// ---------------- kernel 2: h[row][f] = sum_split hp[split][row][f] (float4-vectorized) ----------------
__global__ __launch_bounds__(256) void k_hsum(const float4* __restrict__ hp,
                                              float4* __restrict__ h) {
    int t = blockIdx.x * 256 + threadIdx.x;   // 0 .. 65535 float4s
    float4 s; s.x = 0.f; s.y = 0.f; s.z = 0.f; s.w = 0.f;
#pragma unroll
    for (int sp = 0; sp < SPLITS; ++sp) {
        float4 v = hp[(size_t)sp * (ROWS * 4) + t];
        s.x += v.x; s.y += v.y; s.z += v.z; s.w += v.w;
    }
    h[t] = s;
}

// ---------------- kernel 3: out[o][g] = 0.25 * sum_n (sum_f h[n][o][f]*W[n][f][g] + b[n][g]) ----------------
__global__ __launch_bounds__(256) void k_out(const float* __restrict__ h,
                                             const float* __restrict__ Ws,
                                             const float* __restrict__ bs,
                                             float* __restrict__ out) {
    __shared__ float Wsm[N_ENS * 16 * 16];
    __shared__ float bsm[N_ENS * 16];
    int tid = threadIdx.x;
#pragma unroll
    for (int r = 0; r < 4; ++r) Wsm[tid + 256 * r] = Ws[tid + 256 * r];
    if (tid < 64) bsm[tid] = bs[tid];
    __syncthreads();

    int idx = blockIdx.x * 256 + tid;   // 0..65535
    int o = idx >> 4;
    int gg = idx & 15;
    float s = 0.0f;
#pragma unroll
    for (int n = 0; n < N_ENS; ++n) {
        const float* hr = h + ((size_t)(n * N_OUT + o) << 4);
        float t = 0.0f;
#pragma unroll
        for (int f = 0; f < 16; ++f)
            t = fmaf(hr[f], Wsm[n * 256 + f * 16 + gg], t);
        s += t + bsm[n * 16 + gg];
    }
    out[idx] = 0.25f * s;
}

extern "C" void kernel_launch(void* const* d_in, const int* in_sizes, int n_in,
                              void* d_out, int out_size, void* d_ws, size_t ws_size,
                              hipStream_t stream) {
    const float* x  = (const float*)d_in[0];   // [1, 16384, 16]
    const float* As = (const float*)d_in[1];   // [4, 4096, 16384]
    const float* Ws = (const float*)d_in[2];   // [4, 16, 16]
    const float* bs = (const float*)d_in[3];   // [4, 16]
    float* out = (float*)d_out;                // [1, 4096, 16]

    float* hp = (float*)d_ws;                                     // 4 MB: [4][16384][16]
    float* h  = (float*)((char*)d_ws + (size_t)32 * 1024 * 1024); // 1 MB: [16384][16]

    // hp/h are fully overwritten every call -> no memset needed despite 0xAA poison.
    k_main<<<128 * SPLITS, 128, 0, stream>>>(As, x, hp);
    k_hsum<<<(ROWS * 16 / 4) / 256, 256, 0, stream>>>((const float4*)hp, (float4*)h);
    k_out<<<(N_OUT * 16) / 256, 256, 0, stream>>>(h, Ws, bs, out);
}